// Round 9
// baseline (179.545 us; speedup 1.0000x reference)
//
#include <hip/hip_runtime.h>
#include <math.h>

typedef __bf16 bf16;
typedef __bf16 bf16x4 __attribute__((ext_vector_type(4)));
typedef __bf16 bf16x8 __attribute__((ext_vector_type(8)));
typedef float f32x4 __attribute__((ext_vector_type(4)));

// ---------------------------------------------------------------------------
// async global->LDS, 16B per lane. LDS dest is wave-uniform base + lane*16;
// the GLOBAL side is a per-lane address -> arbitrary gather/swizzle is legal.
// ---------------------------------------------------------------------------
__device__ __forceinline__ void async_copy16(const void* g, void* l) {
  __builtin_amdgcn_global_load_lds(
      (__attribute__((address_space(1))) void*)(const_cast<void*>(g)),
      (__attribute__((address_space(3))) void*)(l),
      16, 0, 0);
}

// ---------------------------------------------------------------------------
// merged prep: f32->bf16 convert of x + both weight transposes in ONE launch
// ---------------------------------------------------------------------------
__device__ __forceinline__ void transpose_tile(
    const float* __restrict__ in, bf16* __restrict__ out, int R, int C,
    int bxi, int byi) {
  __shared__ float tile[32][33];
  int bx = bxi * 32, by = byi * 32;
  int tx = threadIdx.x & 31;
  int ty = threadIdx.x >> 5;  // 0..7
#pragma unroll
  for (int i = 0; i < 32; i += 8)
    tile[ty + i][tx] = in[(size_t)(by + ty + i) * C + bx + tx];
  __syncthreads();
#pragma unroll
  for (int i = 0; i < 32; i += 8)
    out[(size_t)(bx + ty + i) * R + by + tx] = (bf16)tile[tx][ty + i];
}

__global__ __launch_bounds__(256) void prep_kernel(
    const float* __restrict__ x, bf16* __restrict__ xb,
    const float* __restrict__ w_qkv, bf16* __restrict__ wqkvT,
    const float* __restrict__ w_o, bf16* __restrict__ woT) {
  int blk = blockIdx.x;
  if (blk < 4096) {
    int i = blk * 1024 + threadIdx.x * 4;
    float4 v = *(const float4*)(x + i);
    bf16x4 o;
    o[0] = (bf16)v.x; o[1] = (bf16)v.y; o[2] = (bf16)v.z; o[3] = (bf16)v.w;
    *(bf16x4*)(xb + i) = o;
  } else if (blk < 7168) {
    int tb = blk - 4096;
    transpose_tile(w_qkv, wqkvT, 1024, 3072, tb % 96, tb / 96);
  } else {
    int tb = blk - 7168;
    transpose_tile(w_o, woT, 1024, 1024, tb % 32, tb / 32);
  }
}

// ---------------------------------------------------------------------------
// GEMM mainloop, BK=64 double-staged (one barrier pair per 64 k-cols, 32
// MFMA/wave between barriers), XOR-swizzled LDS (16B chunks: slot =
// row*8 + (ch ^ (row&7)) -> conflict-free ds_read_b128), TRANSPOSED D via
// operand swap: acc[mi][ni] holds D^T tile (row=feature quad*4+r,
// col=token lane&15) so epilogues store 4 consecutive features per lane.
// A row-major [M,K] (tokens), Bt row-major [N,K] (features).
// ---------------------------------------------------------------------------
__device__ __forceinline__ void gemm_mainloop64(
    const bf16* __restrict__ A, const bf16* __restrict__ Bt, int K,
    int bm, int bn, bf16* As, bf16* Bs, f32x4 (&acc)[4][4]) {
  int tid = threadIdx.x;
  int w = tid >> 6, lane = tid & 63;
  int wm = w & 1, wn = w >> 1;
  int col = lane & 15, quad = lane >> 4;

  // staging: wave w stages rows [w*32, w*32+32), 4 copies per matrix;
  // lane -> row +(lane>>3), LDS 16B slot lane&7 holds global chunk
  // (lane&7)^(row&7)
  int srow = w * 32 + (lane >> 3);

  for (int k0 = 0; k0 < K; k0 += 64) {
    __syncthreads();
#pragma unroll
    for (int c = 0; c < 4; c++) {
      int r = srow + c * 8;
      int ch = (lane & 7) ^ (r & 7);
      async_copy16(A + (size_t)(bm * 128 + r) * K + k0 + ch * 8,
                   As + (w * 32 + c * 8) * 64);
      async_copy16(Bt + (size_t)(bn * 128 + r) * K + k0 + ch * 8,
                   Bs + (w * 32 + c * 8) * 64);
    }
    __syncthreads();

#pragma unroll
    for (int ks = 0; ks < 2; ks++) {
      bf16x8 af[4], bfr[4];
#pragma unroll
      for (int mi = 0; mi < 4; mi++) {
        int m = wm * 64 + mi * 16 + col;
        af[mi] =
            *(const bf16x8*)(As + m * 64 + ((((ks << 2) + quad)) ^ (m & 7)) * 8);
      }
#pragma unroll
      for (int ni = 0; ni < 4; ni++) {
        int n = wn * 64 + ni * 16 + col;
        bfr[ni] =
            *(const bf16x8*)(Bs + n * 64 + ((((ks << 2) + quad)) ^ (n & 7)) * 8);
      }
#pragma unroll
      for (int mi = 0; mi < 4; mi++)
#pragma unroll
        for (int ni = 0; ni < 4; ni++)
          acc[mi][ni] = __builtin_amdgcn_mfma_f32_16x16x32_bf16(
              bfr[ni], af[mi], acc[mi][ni], 0, 0, 0);  // transposed D
    }
  }
}

// ---------------------------------------------------------------------------
// QKV projection. Blocks are pure-Q / pure-K / pure-V (128 | 1024).
// Q,K scattered [B,H,T,HD] with bf16x4 stores (4 consecutive hd);
// V scattered TRANSPOSED [B,H,HD,T] (4 scalar stores per tile).
// ---------------------------------------------------------------------------
__global__ __launch_bounds__(256) void gemm_qkv_kernel(
    const bf16* __restrict__ A, const bf16* __restrict__ Bt,
    const float* __restrict__ bias, bf16* __restrict__ qb,
    bf16* __restrict__ kb, bf16* __restrict__ vtb) {
  __shared__ bf16 As[128 * 64];
  __shared__ bf16 Bs[128 * 64];
  f32x4 acc[4][4] = {};
  int bm = blockIdx.x, bn = blockIdx.y;
  gemm_mainloop64(A, Bt, 1024, bm, bn, As, Bs, acc);

  int tid = threadIdx.x;
  int w = tid >> 6, lane = tid & 63;
  int wm = w & 1, wn = w >> 1;
  int col = lane & 15, quad = lane >> 4;

#pragma unroll
  for (int ni = 0; ni < 4; ni++) {
    int f0 = bn * 128 + wn * 64 + ni * 16 + quad * 4;  // 4 consecutive feats
    float4 b4 = *(const float4*)(bias + f0);
    int which = f0 >> 10;  // 0=Q 1=K 2=V (uniform per block)
    int dd = f0 & 1023;
    int h = dd >> 6, hd0 = dd & 63;
    if (which == 2) {
#pragma unroll
      for (int mi = 0; mi < 4; mi++) {
        int tok = bm * 128 + wm * 64 + mi * 16 + col;
        int b = tok >> 11, t = tok & 2047;
        size_t base = ((size_t)(b * 16 + h) * 64 + hd0) * 2048 + t;
        vtb[base] = (bf16)(acc[mi][ni][0] + b4.x);
        vtb[base + 2048] = (bf16)(acc[mi][ni][1] + b4.y);
        vtb[base + 4096] = (bf16)(acc[mi][ni][2] + b4.z);
        vtb[base + 6144] = (bf16)(acc[mi][ni][3] + b4.w);
      }
    } else {
      bf16* dst = (which == 0) ? qb : kb;
#pragma unroll
      for (int mi = 0; mi < 4; mi++) {
        int tok = bm * 128 + wm * 64 + mi * 16 + col;
        int b = tok >> 11, t = tok & 2047;
        bf16x4 pk;
        pk[0] = (bf16)(acc[mi][ni][0] + b4.x);
        pk[1] = (bf16)(acc[mi][ni][1] + b4.y);
        pk[2] = (bf16)(acc[mi][ni][2] + b4.z);
        pk[3] = (bf16)(acc[mi][ni][3] + b4.w);
        *(bf16x4*)&dst[((size_t)(b * 16 + h) * 2048 + t) * 64 + hd0] = pk;
      }
    }
  }
}

// ---------------------------------------------------------------------------
// Output projection: out(f32) = yb @ woT^T + b_o; float4 stores (4
// consecutive features per lane, 16B aligned).
// ---------------------------------------------------------------------------
__global__ __launch_bounds__(256) void gemm_out_kernel(
    const bf16* __restrict__ A, const bf16* __restrict__ Bt,
    const float* __restrict__ bias, float* __restrict__ outp) {
  __shared__ bf16 As[128 * 64];
  __shared__ bf16 Bs[128 * 64];
  f32x4 acc[4][4] = {};
  int bm = blockIdx.x, bn = blockIdx.y;
  gemm_mainloop64(A, Bt, 1024, bm, bn, As, Bs, acc);

  int tid = threadIdx.x;
  int w = tid >> 6, lane = tid & 63;
  int wm = w & 1, wn = w >> 1;
  int col = lane & 15, quad = lane >> 4;

#pragma unroll
  for (int ni = 0; ni < 4; ni++) {
    int f0 = bn * 128 + wn * 64 + ni * 16 + quad * 4;
    float4 b4 = *(const float4*)(bias + f0);
#pragma unroll
    for (int mi = 0; mi < 4; mi++) {
      int tok = bm * 128 + wm * 64 + mi * 16 + col;
      float4 ov;
      ov.x = acc[mi][ni][0] + b4.x;
      ov.y = acc[mi][ni][1] + b4.y;
      ov.z = acc[mi][ni][2] + b4.z;
      ov.w = acc[mi][ni][3] + b4.w;
      *(float4*)(outp + (size_t)tok * 1024 + f0) = ov;
    }
  }
}

// ---------------------------------------------------------------------------
// Flash attention (causal), transposed-S form (round-8 winner, unchanged):
//  * qt permutation: each CU's 4 resident blocks sum to exactly 66 tiles.
//  * two K/V tiles staged per barrier pair (double LDS buffers).
//  * P half-strip Pl[4][16][40]; PV split into ks-halves. LDS 37.9 KB.
// No running max (|s| <= ~4 after 1/32 prescale -> exp safe in f32).
// ---------------------------------------------------------------------------
__global__ __launch_bounds__(256, 4) void attn_kernel(
    const bf16* __restrict__ qb, const bf16* __restrict__ kb,
    const bf16* __restrict__ vtb, bf16* __restrict__ y) {
  __shared__ bf16 Ks[2][64 * 64];  // swizzled K tiles  [t][d]
  __shared__ bf16 Vs[2][64 * 64];  // swizzled V^T tiles [d][t]
  __shared__ bf16 Pl[4][16][40];   // per-wave P half-strip [q][t0..31 + pad]

  int idx = blockIdx.x;
  int qp = idx >> 5;
  int qt = (qp < 8) ? 31 - qp
           : (qp < 16) ? qp - 8
           : (qp < 24) ? 39 - qp
                       : qp - 16;
  int bh = idx & 31;
  int b = bh >> 4, h = bh & 15;
  int tid = threadIdx.x, w = tid >> 6, lane = tid & 63;
  int col = lane & 15, quad = lane >> 4;

  const bf16* Qh = qb + (size_t)bh * (2048 * 64);
  const bf16* Kh = kb + (size_t)bh * (2048 * 64);
  const bf16* Vth = vtb + (size_t)bh * (64 * 2048);

  // Q frags (B-operand of S^T = K*Q^T), pre-scaled by 1/32 (exact)
  int qrow = qt * 64 + w * 16 + col;
  bf16x8 aq[2];
#pragma unroll
  for (int ks = 0; ks < 2; ks++) {
    aq[ks] = *(const bf16x8*)(Qh + (size_t)qrow * 64 + ks * 32 + quad * 8);
#pragma unroll
    for (int e = 0; e < 8; e++)
      aq[ks][e] = (bf16)((float)aq[ks][e] * 0.03125f);
  }

  int r0 = w * 16 + (lane >> 3);
  int r1 = r0 + 8;
  int ch0 = (lane & 7) ^ (r0 & 7);
  int ch1 = (lane & 7) ^ (r1 & 7);
  size_t koff0 = (size_t)r0 * 64 + ch0 * 8;
  size_t koff1 = (size_t)r1 * 64 + ch1 * 8;
  size_t voff0 = (size_t)r0 * 2048 + ch0 * 8;
  size_t voff1 = (size_t)r1 * 2048 + ch1 * 8;
  int lw0 = (w * 16) * 64;
  int lw1 = (w * 16 + 8) * 64;

  float l_part = 0.f;
  f32x4 ot[4] = {};
  int qglob = qt * 64 + w * 16 + col;

  auto stage = [&](int j, int buf) {
    const bf16* Kt = Kh + (size_t)j * 64 * 64;
    const bf16* Vt_ = Vth + (size_t)j * 64;
    async_copy16(Kt + koff0, Ks[buf] + lw0);
    async_copy16(Kt + koff1, Ks[buf] + lw1);
    async_copy16(Vt_ + voff0, Vs[buf] + lw0);
    async_copy16(Vt_ + voff1, Vs[buf] + lw1);
  };

  auto tile_compute = [&](int j, int buf, bool diag) {
    const bf16* Ksb = Ks[buf];
    const bf16* Vsb = Vs[buf];
    f32x4 st[4] = {};
#pragma unroll
    for (int ks = 0; ks < 2; ks++)
#pragma unroll
      for (int c = 0; c < 4; c++) {
        int t = c * 16 + col;
        int slot = t * 8 + (((ks << 2) + quad) ^ (t & 7));
        bf16x8 ak = *(const bf16x8*)(Ksb + slot * 8);
        st[c] = __builtin_amdgcn_mfma_f32_16x16x32_bf16(ak, aq[ks], st[c],
                                                        0, 0, 0);
      }
#pragma unroll
    for (int half = 0; half < 2; half++) {
#pragma unroll
      for (int cc = 0; cc < 2; cc++) {
        int c = half * 2 + cc;
        bf16x4 pk;
#pragma unroll
        for (int r = 0; r < 4; r++) {
          int tglob = j * 64 + c * 16 + quad * 4 + r;
          float pv = (diag && tglob > qglob) ? 0.f : __expf(st[c][r]);
          l_part += pv;
          pk[r] = (bf16)pv;
        }
        *(bf16x4*)&Pl[w][col][cc * 16 + quad * 4] = pk;
      }
      __builtin_amdgcn_sched_barrier(0);
      __builtin_amdgcn_s_waitcnt(0xc07f);  // lgkmcnt(0)
      __builtin_amdgcn_sched_barrier(0);
      bf16x8 ap = *(const bf16x8*)&Pl[w][col][quad * 8];
#pragma unroll
      for (int c = 0; c < 4; c++) {
        int d = c * 16 + col;
        int slot = d * 8 + (((half << 2) + quad) ^ (d & 7));
        bf16x8 av = *(const bf16x8*)(Vsb + slot * 8);
        ot[c] = __builtin_amdgcn_mfma_f32_16x16x32_bf16(av, ap, ot[c],
                                                        0, 0, 0);
      }
    }
  };

  int j = 0;
  for (; j < qt; j += 2) {
    __syncthreads();
    stage(j, 0);
    stage(j + 1, 1);
    __syncthreads();
    tile_compute(j, 0, false);
    tile_compute(j + 1, 1, j + 1 == qt);
  }
  if (j == qt) {
    __syncthreads();
    stage(j, 0);
    __syncthreads();
    tile_compute(j, 0, true);
  }

  float sum = l_part;
  sum += __shfl_xor(sum, 16, 64);
  sum += __shfl_xor(sum, 32, 64);
  float inv = 1.f / sum;
  int tq = qt * 64 + w * 16 + col;
  bf16* yrow = y + ((size_t)(b * 2048 + tq)) * 1024 + h * 64;
#pragma unroll
  for (int c = 0; c < 4; c++) {
    bf16x4 pk;
#pragma unroll
    for (int r = 0; r < 4; r++) pk[r] = (bf16)(ot[c][r] * inv);
    *(bf16x4*)(yrow + c * 16 + quad * 4) = pk;
  }
}

// ---------------------------------------------------------------------------
extern "C" void kernel_launch(void* const* d_in, const int* in_sizes, int n_in,
                              void* d_out, int out_size, void* d_ws,
                              size_t ws_size, hipStream_t stream) {
  const float* x = (const float*)d_in[0];      // [2,2048,1024] f32
  const float* w_qkv = (const float*)d_in[1];  // [1024,3072] f32
  const float* b_qkv = (const float*)d_in[2];  // [3072] f32
  const float* w_o = (const float*)d_in[3];    // [1024,1024] f32
  const float* b_o = (const float*)d_in[4];    // [1024] f32
  float* out = (float*)d_out;                  // [2,2048,1024] f32

  char* p = (char*)d_ws;
  bf16* xb    = (bf16*)p; p += (size_t)4096 * 1024 * 2;
  bf16* wqkvT = (bf16*)p; p += (size_t)3072 * 1024 * 2;
  bf16* woT   = (bf16*)p; p += (size_t)1024 * 1024 * 2;
  bf16* qb    = (bf16*)p; p += (size_t)2 * 16 * 2048 * 64 * 2;
  bf16* kb    = (bf16*)p; p += (size_t)2 * 16 * 2048 * 64 * 2;
  bf16* vtb   = (bf16*)p; p += (size_t)2 * 16 * 64 * 2048 * 2;
  bf16* yb    = (bf16*)p; p += (size_t)4096 * 1024 * 2;

  prep_kernel<<<8192, 256, 0, stream>>>(x, xb, w_qkv, wqkvT, w_o, woT);
  gemm_qkv_kernel<<<dim3(32, 24), 256, 0, stream>>>(
      xb, wqkvT, b_qkv, qb, kb, vtb);
  attn_kernel<<<1024, 256, 0, stream>>>(qb, kb, vtb, yb);
  gemm_out_kernel<<<dim3(32, 8), 256, 0, stream>>>(yb, woT, b_o, out);
}

// Round 10
// 165.240 us; speedup vs baseline: 1.0866x; 1.0866x over previous
//
#include <hip/hip_runtime.h>
#include <math.h>

typedef __bf16 bf16;
typedef __bf16 bf16x4 __attribute__((ext_vector_type(4)));
typedef __bf16 bf16x8 __attribute__((ext_vector_type(8)));
typedef float f32x4 __attribute__((ext_vector_type(4)));

// ---------------------------------------------------------------------------
// async global->LDS, 16B per lane. LDS dest is wave-uniform base + lane*16;
// the GLOBAL side is a per-lane address -> arbitrary gather/swizzle is legal.
// ---------------------------------------------------------------------------
__device__ __forceinline__ void async_copy16(const void* g, void* l) {
  __builtin_amdgcn_global_load_lds(
      (__attribute__((address_space(1))) void*)(const_cast<void*>(g)),
      (__attribute__((address_space(3))) void*)(l),
      16, 0, 0);
}

// ---------------------------------------------------------------------------
// merged prep: f32->bf16 convert of x + both weight transposes in ONE launch
// ---------------------------------------------------------------------------
__device__ __forceinline__ void transpose_tile(
    const float* __restrict__ in, bf16* __restrict__ out, int R, int C,
    int bxi, int byi) {
  __shared__ float tile[32][33];
  int bx = bxi * 32, by = byi * 32;
  int tx = threadIdx.x & 31;
  int ty = threadIdx.x >> 5;  // 0..7
#pragma unroll
  for (int i = 0; i < 32; i += 8)
    tile[ty + i][tx] = in[(size_t)(by + ty + i) * C + bx + tx];
  __syncthreads();
#pragma unroll
  for (int i = 0; i < 32; i += 8)
    out[(size_t)(bx + ty + i) * R + by + tx] = (bf16)tile[tx][ty + i];
}

__global__ __launch_bounds__(256) void prep_kernel(
    const float* __restrict__ x, bf16* __restrict__ xb,
    const float* __restrict__ w_qkv, bf16* __restrict__ wqkvT,
    const float* __restrict__ w_o, bf16* __restrict__ woT) {
  int blk = blockIdx.x;
  if (blk < 4096) {
    int i = blk * 1024 + threadIdx.x * 4;
    float4 v = *(const float4*)(x + i);
    bf16x4 o;
    o[0] = (bf16)v.x; o[1] = (bf16)v.y; o[2] = (bf16)v.z; o[3] = (bf16)v.w;
    *(bf16x4*)(xb + i) = o;
  } else if (blk < 7168) {
    int tb = blk - 4096;
    transpose_tile(w_qkv, wqkvT, 1024, 3072, tb % 96, tb / 96);
  } else {
    int tb = blk - 7168;
    transpose_tile(w_o, woT, 1024, 1024, tb % 32, tb / 32);
  }
}

// ---------------------------------------------------------------------------
// QKV projection, 64x128 tile (M x N), BK=64 double-staged, XOR-swizzled LDS,
// TRANSPOSED D (operand swap) -> vectorized feature-major epilogue stores.
// Grid 64x24 = 1536 blocks = 6/CU: doubles per-CU independent barrier
// streams vs round 9's 3/CU (drain-coverage was the bottleneck).
// Wave w owns a 32m x 64n quadrant: acc[2][4].
// Blocks are pure-Q / pure-K / pure-V (128 | 1024).
// ---------------------------------------------------------------------------
__global__ __launch_bounds__(256) void gemm_qkv_kernel(
    const bf16* __restrict__ A, const bf16* __restrict__ Bt,
    const float* __restrict__ bias, bf16* __restrict__ qb,
    bf16* __restrict__ kb, bf16* __restrict__ vtb) {
  __shared__ bf16 As[64 * 64];   // 8 KB, swizzled
  __shared__ bf16 Bs[128 * 64];  // 16 KB, swizzled
  int bm = blockIdx.x, bn = blockIdx.y;
  int tid = threadIdx.x;
  int w = tid >> 6, lane = tid & 63;
  int wm = w & 1, wn = w >> 1;
  int col = lane & 15, quad = lane >> 4;

  const bf16* Ab = A + (size_t)(bm * 64) * 1024;
  const bf16* Bb = Bt + (size_t)(bn * 128) * 1024;
  f32x4 acc[2][4] = {};

  int lrow = lane >> 3;          // 0..7
  int lch = lane & 7;            // LDS 16B slot

  for (int k0 = 0; k0 < 1024; k0 += 64) {
    __syncthreads();
#pragma unroll
    for (int c = 0; c < 2; c++) {  // A: 64 rows, wave stages 16
      int r = w * 16 + c * 8 + lrow;
      int ch = lch ^ (r & 7);
      async_copy16(Ab + (size_t)r * 1024 + k0 + ch * 8,
                   As + (w * 16 + c * 8) * 64);
    }
#pragma unroll
    for (int c = 0; c < 4; c++) {  // B: 128 rows, wave stages 32
      int r = w * 32 + c * 8 + lrow;
      int ch = lch ^ (r & 7);
      async_copy16(Bb + (size_t)r * 1024 + k0 + ch * 8,
                   Bs + (w * 32 + c * 8) * 64);
    }
    __syncthreads();

#pragma unroll
    for (int ks = 0; ks < 2; ks++) {
      bf16x8 af[2], bfr[4];
#pragma unroll
      for (int mi = 0; mi < 2; mi++) {
        int m = wm * 32 + mi * 16 + col;
        af[mi] =
            *(const bf16x8*)(As + m * 64 + (((ks << 2) + quad) ^ (m & 7)) * 8);
      }
#pragma unroll
      for (int ni = 0; ni < 4; ni++) {
        int n = wn * 64 + ni * 16 + col;
        bfr[ni] =
            *(const bf16x8*)(Bs + n * 64 + (((ks << 2) + quad) ^ (n & 7)) * 8);
      }
#pragma unroll
      for (int mi = 0; mi < 2; mi++)
#pragma unroll
        for (int ni = 0; ni < 4; ni++)
          acc[mi][ni] = __builtin_amdgcn_mfma_f32_16x16x32_bf16(
              bfr[ni], af[mi], acc[mi][ni], 0, 0, 0);  // transposed D
    }
  }

#pragma unroll
  for (int ni = 0; ni < 4; ni++) {
    int f0 = bn * 128 + wn * 64 + ni * 16 + quad * 4;  // 4 consecutive feats
    float4 b4 = *(const float4*)(bias + f0);
    int which = f0 >> 10;  // 0=Q 1=K 2=V (uniform per block)
    int dd = f0 & 1023;
    int h = dd >> 6, hd0 = dd & 63;
    if (which == 2) {
#pragma unroll
      for (int mi = 0; mi < 2; mi++) {
        int tok = bm * 64 + wm * 32 + mi * 16 + col;
        int b = tok >> 11, t = tok & 2047;
        size_t base = ((size_t)(b * 16 + h) * 64 + hd0) * 2048 + t;
        vtb[base] = (bf16)(acc[mi][ni][0] + b4.x);
        vtb[base + 2048] = (bf16)(acc[mi][ni][1] + b4.y);
        vtb[base + 4096] = (bf16)(acc[mi][ni][2] + b4.z);
        vtb[base + 6144] = (bf16)(acc[mi][ni][3] + b4.w);
      }
    } else {
      bf16* dst = (which == 0) ? qb : kb;
#pragma unroll
      for (int mi = 0; mi < 2; mi++) {
        int tok = bm * 64 + wm * 32 + mi * 16 + col;
        int b = tok >> 11, t = tok & 2047;
        bf16x4 pk;
        pk[0] = (bf16)(acc[mi][ni][0] + b4.x);
        pk[1] = (bf16)(acc[mi][ni][1] + b4.y);
        pk[2] = (bf16)(acc[mi][ni][2] + b4.z);
        pk[3] = (bf16)(acc[mi][ni][3] + b4.w);
        *(bf16x4*)&dst[((size_t)(b * 16 + h) * 2048 + t) * 64 + hd0] = pk;
      }
    }
  }
}

// ---------------------------------------------------------------------------
// Output projection, 64x64 tile, BK=64 double-staged, swizzled, transposed D.
// Grid 64x16 = 1024 blocks = 4/CU (round 9 had 1/CU -> zero drain overlap).
// Wave w owns 32m x 32n: acc[2][2]. float4 epilogue stores.
// ---------------------------------------------------------------------------
__global__ __launch_bounds__(256) void gemm_out_kernel(
    const bf16* __restrict__ A, const bf16* __restrict__ Bt,
    const float* __restrict__ bias, float* __restrict__ outp) {
  __shared__ bf16 As[64 * 64];  // 8 KB
  __shared__ bf16 Bs[64 * 64];  // 8 KB
  int bm = blockIdx.x, bn = blockIdx.y;
  int tid = threadIdx.x;
  int w = tid >> 6, lane = tid & 63;
  int wm = w & 1, wn = w >> 1;
  int col = lane & 15, quad = lane >> 4;

  const bf16* Ab = A + (size_t)(bm * 64) * 1024;
  const bf16* Bb = Bt + (size_t)(bn * 64) * 1024;
  f32x4 acc[2][2] = {};

  int lrow = lane >> 3;
  int lch = lane & 7;

  for (int k0 = 0; k0 < 1024; k0 += 64) {
    __syncthreads();
#pragma unroll
    for (int c = 0; c < 2; c++) {
      int r = w * 16 + c * 8 + lrow;
      int ch = lch ^ (r & 7);
      async_copy16(Ab + (size_t)r * 1024 + k0 + ch * 8,
                   As + (w * 16 + c * 8) * 64);
      async_copy16(Bb + (size_t)r * 1024 + k0 + ch * 8,
                   Bs + (w * 16 + c * 8) * 64);
    }
    __syncthreads();

#pragma unroll
    for (int ks = 0; ks < 2; ks++) {
      bf16x8 af[2], bfr[2];
#pragma unroll
      for (int mi = 0; mi < 2; mi++) {
        int m = wm * 32 + mi * 16 + col;
        af[mi] =
            *(const bf16x8*)(As + m * 64 + (((ks << 2) + quad) ^ (m & 7)) * 8);
      }
#pragma unroll
      for (int ni = 0; ni < 2; ni++) {
        int n = wn * 32 + ni * 16 + col;
        bfr[ni] =
            *(const bf16x8*)(Bs + n * 64 + (((ks << 2) + quad) ^ (n & 7)) * 8);
      }
#pragma unroll
      for (int mi = 0; mi < 2; mi++)
#pragma unroll
        for (int ni = 0; ni < 2; ni++)
          acc[mi][ni] = __builtin_amdgcn_mfma_f32_16x16x32_bf16(
              bfr[ni], af[mi], acc[mi][ni], 0, 0, 0);  // transposed D
    }
  }

#pragma unroll
  for (int ni = 0; ni < 2; ni++) {
    int f0 = bn * 64 + wn * 32 + ni * 16 + quad * 4;
    float4 b4 = *(const float4*)(bias + f0);
#pragma unroll
    for (int mi = 0; mi < 2; mi++) {
      int tok = bm * 64 + wm * 32 + mi * 16 + col;
      float4 ov;
      ov.x = acc[mi][ni][0] + b4.x;
      ov.y = acc[mi][ni][1] + b4.y;
      ov.z = acc[mi][ni][2] + b4.z;
      ov.w = acc[mi][ni][3] + b4.w;
      *(float4*)(outp + (size_t)tok * 1024 + f0) = ov;
    }
  }
}

// ---------------------------------------------------------------------------
// Flash attention (causal), transposed-S form (round-8 winner, unchanged):
//  * qt permutation: each CU's 4 resident blocks sum to exactly 66 tiles.
//  * two K/V tiles staged per barrier pair (double LDS buffers).
//  * P half-strip Pl[4][16][40]; PV split into ks-halves. LDS 37.9 KB.
// No running max (|s| <= ~4 after 1/32 prescale -> exp safe in f32).
// ---------------------------------------------------------------------------
__global__ __launch_bounds__(256, 4) void attn_kernel(
    const bf16* __restrict__ qb, const bf16* __restrict__ kb,
    const bf16* __restrict__ vtb, bf16* __restrict__ y) {
  __shared__ bf16 Ks[2][64 * 64];  // swizzled K tiles  [t][d]
  __shared__ bf16 Vs[2][64 * 64];  // swizzled V^T tiles [d][t]
  __shared__ bf16 Pl[4][16][40];   // per-wave P half-strip [q][t0..31 + pad]

  int idx = blockIdx.x;
  int qp = idx >> 5;
  int qt = (qp < 8) ? 31 - qp
           : (qp < 16) ? qp - 8
           : (qp < 24) ? 39 - qp
                       : qp - 16;
  int bh = idx & 31;
  int b = bh >> 4, h = bh & 15;
  int tid = threadIdx.x, w = tid >> 6, lane = tid & 63;
  int col = lane & 15, quad = lane >> 4;

  const bf16* Qh = qb + (size_t)bh * (2048 * 64);
  const bf16* Kh = kb + (size_t)bh * (2048 * 64);
  const bf16* Vth = vtb + (size_t)bh * (64 * 2048);

  int qrow = qt * 64 + w * 16 + col;
  bf16x8 aq[2];
#pragma unroll
  for (int ks = 0; ks < 2; ks++) {
    aq[ks] = *(const bf16x8*)(Qh + (size_t)qrow * 64 + ks * 32 + quad * 8);
#pragma unroll
    for (int e = 0; e < 8; e++)
      aq[ks][e] = (bf16)((float)aq[ks][e] * 0.03125f);
  }

  int r0 = w * 16 + (lane >> 3);
  int r1 = r0 + 8;
  int ch0 = (lane & 7) ^ (r0 & 7);
  int ch1 = (lane & 7) ^ (r1 & 7);
  size_t koff0 = (size_t)r0 * 64 + ch0 * 8;
  size_t koff1 = (size_t)r1 * 64 + ch1 * 8;
  size_t voff0 = (size_t)r0 * 2048 + ch0 * 8;
  size_t voff1 = (size_t)r1 * 2048 + ch1 * 8;
  int lw0 = (w * 16) * 64;
  int lw1 = (w * 16 + 8) * 64;

  float l_part = 0.f;
  f32x4 ot[4] = {};
  int qglob = qt * 64 + w * 16 + col;

  auto stage = [&](int j, int buf) {
    const bf16* Kt = Kh + (size_t)j * 64 * 64;
    const bf16* Vt_ = Vth + (size_t)j * 64;
    async_copy16(Kt + koff0, Ks[buf] + lw0);
    async_copy16(Kt + koff1, Ks[buf] + lw1);
    async_copy16(Vt_ + voff0, Vs[buf] + lw0);
    async_copy16(Vt_ + voff1, Vs[buf] + lw1);
  };

  auto tile_compute = [&](int j, int buf, bool diag) {
    const bf16* Ksb = Ks[buf];
    const bf16* Vsb = Vs[buf];
    f32x4 st[4] = {};
#pragma unroll
    for (int ks = 0; ks < 2; ks++)
#pragma unroll
      for (int c = 0; c < 4; c++) {
        int t = c * 16 + col;
        int slot = t * 8 + (((ks << 2) + quad) ^ (t & 7));
        bf16x8 ak = *(const bf16x8*)(Ksb + slot * 8);
        st[c] = __builtin_amdgcn_mfma_f32_16x16x32_bf16(ak, aq[ks], st[c],
                                                        0, 0, 0);
      }
#pragma unroll
    for (int half = 0; half < 2; half++) {
#pragma unroll
      for (int cc = 0; cc < 2; cc++) {
        int c = half * 2 + cc;
        bf16x4 pk;
#pragma unroll
        for (int r = 0; r < 4; r++) {
          int tglob = j * 64 + c * 16 + quad * 4 + r;
          float pv = (diag && tglob > qglob) ? 0.f : __expf(st[c][r]);
          l_part += pv;
          pk[r] = (bf16)pv;
        }
        *(bf16x4*)&Pl[w][col][cc * 16 + quad * 4] = pk;
      }
      __builtin_amdgcn_sched_barrier(0);
      __builtin_amdgcn_s_waitcnt(0xc07f);  // lgkmcnt(0)
      __builtin_amdgcn_sched_barrier(0);
      bf16x8 ap = *(const bf16x8*)&Pl[w][col][quad * 8];
#pragma unroll
      for (int c = 0; c < 4; c++) {
        int d = c * 16 + col;
        int slot = d * 8 + (((half << 2) + quad) ^ (d & 7));
        bf16x8 av = *(const bf16x8*)(Vsb + slot * 8);
        ot[c] = __builtin_amdgcn_mfma_f32_16x16x32_bf16(av, ap, ot[c],
                                                        0, 0, 0);
      }
    }
  };

  int j = 0;
  for (; j < qt; j += 2) {
    __syncthreads();
    stage(j, 0);
    stage(j + 1, 1);
    __syncthreads();
    tile_compute(j, 0, false);
    tile_compute(j + 1, 1, j + 1 == qt);
  }
  if (j == qt) {
    __syncthreads();
    stage(j, 0);
    __syncthreads();
    tile_compute(j, 0, true);
  }

  float sum = l_part;
  sum += __shfl_xor(sum, 16, 64);
  sum += __shfl_xor(sum, 32, 64);
  float inv = 1.f / sum;
  int tq = qt * 64 + w * 16 + col;
  bf16* yrow = y + ((size_t)(b * 2048 + tq)) * 1024 + h * 64;
#pragma unroll
  for (int c = 0; c < 4; c++) {
    bf16x4 pk;
#pragma unroll
    for (int r = 0; r < 4; r++) pk[r] = (bf16)(ot[c][r] * inv);
    *(bf16x4*)(yrow + c * 16 + quad * 4) = pk;
  }
}

// ---------------------------------------------------------------------------
extern "C" void kernel_launch(void* const* d_in, const int* in_sizes, int n_in,
                              void* d_out, int out_size, void* d_ws,
                              size_t ws_size, hipStream_t stream) {
  const float* x = (const float*)d_in[0];      // [2,2048,1024] f32
  const float* w_qkv = (const float*)d_in[1];  // [1024,3072] f32
  const float* b_qkv = (const float*)d_in[2];  // [3072] f32
  const float* w_o = (const float*)d_in[3];    // [1024,1024] f32
  const float* b_o = (const float*)d_in[4];    // [1024] f32
  float* out = (float*)d_out;                  // [2,2048,1024] f32

  char* p = (char*)d_ws;
  bf16* xb    = (bf16*)p; p += (size_t)4096 * 1024 * 2;
  bf16* wqkvT = (bf16*)p; p += (size_t)3072 * 1024 * 2;
  bf16* woT   = (bf16*)p; p += (size_t)1024 * 1024 * 2;
  bf16* qb    = (bf16*)p; p += (size_t)2 * 16 * 2048 * 64 * 2;
  bf16* kb    = (bf16*)p; p += (size_t)2 * 16 * 2048 * 64 * 2;
  bf16* vtb   = (bf16*)p; p += (size_t)2 * 16 * 64 * 2048 * 2;
  bf16* yb    = (bf16*)p; p += (size_t)4096 * 1024 * 2;

  prep_kernel<<<8192, 256, 0, stream>>>(x, xb, w_qkv, wqkvT, w_o, woT);
  gemm_qkv_kernel<<<dim3(64, 24), 256, 0, stream>>>(
      xb, wqkvT, b_qkv, qb, kb, vtb);
  attn_kernel<<<1024, 256, 0, stream>>>(qb, kb, vtb, yb);
  gemm_out_kernel<<<dim3(64, 16), 256, 0, stream>>>(yb, woT, b_o, out);
}

// Round 11
// 163.241 us; speedup vs baseline: 1.0999x; 1.0122x over previous
//
#include <hip/hip_runtime.h>
#include <math.h>

typedef __bf16 bf16;
typedef __bf16 bf16x4 __attribute__((ext_vector_type(4)));
typedef __bf16 bf16x8 __attribute__((ext_vector_type(8)));
typedef float f32x4 __attribute__((ext_vector_type(4)));

// ---------------------------------------------------------------------------
// async global->LDS, 16B per lane. LDS dest is wave-uniform base + lane*16;
// the GLOBAL side is a per-lane address -> arbitrary gather/swizzle is legal.
// ---------------------------------------------------------------------------
__device__ __forceinline__ void async_copy16(const void* g, void* l) {
  __builtin_amdgcn_global_load_lds(
      (__attribute__((address_space(1))) void*)(const_cast<void*>(g)),
      (__attribute__((address_space(3))) void*)(l),
      16, 0, 0);
}

// ---------------------------------------------------------------------------
// merged prep: f32->bf16 convert of x + both weight transposes in ONE launch.
// Transpose tile: float4 loads (16B/lane), bf16x4 stores (8B/lane).
// ---------------------------------------------------------------------------
__device__ __forceinline__ void transpose_tile(
    const float* __restrict__ in, bf16* __restrict__ out, int R, int C,
    int bxi, int byi) {
  __shared__ float tile[32][33];
  int bx = bxi * 32, by = byi * 32;
  int tid = threadIdx.x;
  {
    int row = tid >> 3;          // 0..31
    int cq = tid & 7;            // 4-col group
    float4 v = *(const float4*)(in + (size_t)(by + row) * C + bx + cq * 4);
    tile[row][cq * 4 + 0] = v.x;
    tile[row][cq * 4 + 1] = v.y;
    tile[row][cq * 4 + 2] = v.z;
    tile[row][cq * 4 + 3] = v.w;
  }
  __syncthreads();
  {
    int c = tid >> 3;            // output row = bx + c
    int rq = tid & 7;            // 4-row group
    bf16x4 pk;
#pragma unroll
    for (int e = 0; e < 4; e++) pk[e] = (bf16)tile[rq * 4 + e][c];
    *(bf16x4*)(out + (size_t)(bx + c) * R + by + rq * 4) = pk;
  }
}

__global__ __launch_bounds__(256) void prep_kernel(
    const float* __restrict__ x, bf16* __restrict__ xb,
    const float* __restrict__ w_qkv, bf16* __restrict__ wqkvT,
    const float* __restrict__ w_o, bf16* __restrict__ woT) {
  int blk = blockIdx.x;
  if (blk < 4096) {
    int i = blk * 1024 + threadIdx.x * 4;
    float4 v = *(const float4*)(x + i);
    bf16x4 o;
    o[0] = (bf16)v.x; o[1] = (bf16)v.y; o[2] = (bf16)v.z; o[3] = (bf16)v.w;
    *(bf16x4*)(xb + i) = o;
  } else if (blk < 7168) {
    int tb = blk - 4096;
    transpose_tile(w_qkv, wqkvT, 1024, 3072, tb % 96, tb / 96);
  } else {
    int tb = blk - 7168;
    transpose_tile(w_o, woT, 1024, 1024, tb % 32, tb / 32);
  }
}

// ---------------------------------------------------------------------------
// QKV projection, 64x128 tile (M x N), BK=64 double-staged, XOR-swizzled LDS,
// TRANSPOSED D (operand swap) -> vectorized feature-major epilogue stores.
// Grid 64x24 = 1536 blocks = 6/CU. Wave w owns 32m x 64n: acc[2][4].
// Blocks are pure-Q / pure-K / pure-V (128 | 1024).
// ---------------------------------------------------------------------------
__global__ __launch_bounds__(256) void gemm_qkv_kernel(
    const bf16* __restrict__ A, const bf16* __restrict__ Bt,
    const float* __restrict__ bias, bf16* __restrict__ qb,
    bf16* __restrict__ kb, bf16* __restrict__ vtb) {
  __shared__ bf16 As[64 * 64];   // 8 KB, swizzled
  __shared__ bf16 Bs[128 * 64];  // 16 KB, swizzled
  int bm = blockIdx.x, bn = blockIdx.y;
  int tid = threadIdx.x;
  int w = tid >> 6, lane = tid & 63;
  int wm = w & 1, wn = w >> 1;
  int col = lane & 15, quad = lane >> 4;

  const bf16* Ab = A + (size_t)(bm * 64) * 1024;
  const bf16* Bb = Bt + (size_t)(bn * 128) * 1024;
  f32x4 acc[2][4] = {};

  int lrow = lane >> 3;  // 0..7
  int lch = lane & 7;    // LDS 16B slot

  for (int k0 = 0; k0 < 1024; k0 += 64) {
    __syncthreads();
#pragma unroll
    for (int c = 0; c < 2; c++) {  // A: 64 rows, wave stages 16
      int r = w * 16 + c * 8 + lrow;
      int ch = lch ^ (r & 7);
      async_copy16(Ab + (size_t)r * 1024 + k0 + ch * 8,
                   As + (w * 16 + c * 8) * 64);
    }
#pragma unroll
    for (int c = 0; c < 4; c++) {  // B: 128 rows, wave stages 32
      int r = w * 32 + c * 8 + lrow;
      int ch = lch ^ (r & 7);
      async_copy16(Bb + (size_t)r * 1024 + k0 + ch * 8,
                   Bs + (w * 32 + c * 8) * 64);
    }
    __syncthreads();

#pragma unroll
    for (int ks = 0; ks < 2; ks++) {
      bf16x8 af[2], bfr[4];
#pragma unroll
      for (int mi = 0; mi < 2; mi++) {
        int m = wm * 32 + mi * 16 + col;
        af[mi] =
            *(const bf16x8*)(As + m * 64 + (((ks << 2) + quad) ^ (m & 7)) * 8);
      }
#pragma unroll
      for (int ni = 0; ni < 4; ni++) {
        int n = wn * 64 + ni * 16 + col;
        bfr[ni] =
            *(const bf16x8*)(Bs + n * 64 + (((ks << 2) + quad) ^ (n & 7)) * 8);
      }
#pragma unroll
      for (int mi = 0; mi < 2; mi++)
#pragma unroll
        for (int ni = 0; ni < 4; ni++)
          acc[mi][ni] = __builtin_amdgcn_mfma_f32_16x16x32_bf16(
              bfr[ni], af[mi], acc[mi][ni], 0, 0, 0);  // transposed D
    }
  }

#pragma unroll
  for (int ni = 0; ni < 4; ni++) {
    int f0 = bn * 128 + wn * 64 + ni * 16 + quad * 4;  // 4 consecutive feats
    float4 b4 = *(const float4*)(bias + f0);
    int which = f0 >> 10;  // 0=Q 1=K 2=V (uniform per block)
    int dd = f0 & 1023;
    int h = dd >> 6, hd0 = dd & 63;
    if (which == 2) {
#pragma unroll
      for (int mi = 0; mi < 2; mi++) {
        int tok = bm * 64 + wm * 32 + mi * 16 + col;
        int b = tok >> 11, t = tok & 2047;
        size_t base = ((size_t)(b * 16 + h) * 64 + hd0) * 2048 + t;
        vtb[base] = (bf16)(acc[mi][ni][0] + b4.x);
        vtb[base + 2048] = (bf16)(acc[mi][ni][1] + b4.y);
        vtb[base + 4096] = (bf16)(acc[mi][ni][2] + b4.z);
        vtb[base + 6144] = (bf16)(acc[mi][ni][3] + b4.w);
      }
    } else {
      bf16* dst = (which == 0) ? qb : kb;
#pragma unroll
      for (int mi = 0; mi < 2; mi++) {
        int tok = bm * 64 + wm * 32 + mi * 16 + col;
        int b = tok >> 11, t = tok & 2047;
        bf16x4 pk;
        pk[0] = (bf16)(acc[mi][ni][0] + b4.x);
        pk[1] = (bf16)(acc[mi][ni][1] + b4.y);
        pk[2] = (bf16)(acc[mi][ni][2] + b4.z);
        pk[3] = (bf16)(acc[mi][ni][3] + b4.w);
        *(bf16x4*)&dst[((size_t)(b * 16 + h) * 2048 + t) * 64 + hd0] = pk;
      }
    }
  }
}

// ---------------------------------------------------------------------------
// Output projection, 64x64 tile, BK=64 double-staged, swizzled, transposed D.
// Grid 64x16 = 1024 blocks = 4/CU. Wave w owns 32m x 32n: acc[2][2].
// ---------------------------------------------------------------------------
__global__ __launch_bounds__(256) void gemm_out_kernel(
    const bf16* __restrict__ A, const bf16* __restrict__ Bt,
    const float* __restrict__ bias, float* __restrict__ outp) {
  __shared__ bf16 As[64 * 64];  // 8 KB
  __shared__ bf16 Bs[64 * 64];  // 8 KB
  int bm = blockIdx.x, bn = blockIdx.y;
  int tid = threadIdx.x;
  int w = tid >> 6, lane = tid & 63;
  int wm = w & 1, wn = w >> 1;
  int col = lane & 15, quad = lane >> 4;

  const bf16* Ab = A + (size_t)(bm * 64) * 1024;
  const bf16* Bb = Bt + (size_t)(bn * 64) * 1024;
  f32x4 acc[2][2] = {};

  int lrow = lane >> 3;
  int lch = lane & 7;

  for (int k0 = 0; k0 < 1024; k0 += 64) {
    __syncthreads();
#pragma unroll
    for (int c = 0; c < 2; c++) {
      int r = w * 16 + c * 8 + lrow;
      int ch = lch ^ (r & 7);
      async_copy16(Ab + (size_t)r * 1024 + k0 + ch * 8,
                   As + (w * 16 + c * 8) * 64);
      async_copy16(Bb + (size_t)r * 1024 + k0 + ch * 8,
                   Bs + (w * 16 + c * 8) * 64);
    }
    __syncthreads();

#pragma unroll
    for (int ks = 0; ks < 2; ks++) {
      bf16x8 af[2], bfr[2];
#pragma unroll
      for (int mi = 0; mi < 2; mi++) {
        int m = wm * 32 + mi * 16 + col;
        af[mi] =
            *(const bf16x8*)(As + m * 64 + (((ks << 2) + quad) ^ (m & 7)) * 8);
      }
#pragma unroll
      for (int ni = 0; ni < 2; ni++) {
        int n = wn * 32 + ni * 16 + col;
        bfr[ni] =
            *(const bf16x8*)(Bs + n * 64 + (((ks << 2) + quad) ^ (n & 7)) * 8);
      }
#pragma unroll
      for (int mi = 0; mi < 2; mi++)
#pragma unroll
        for (int ni = 0; ni < 2; ni++)
          acc[mi][ni] = __builtin_amdgcn_mfma_f32_16x16x32_bf16(
              bfr[ni], af[mi], acc[mi][ni], 0, 0, 0);  // transposed D
    }
  }

#pragma unroll
  for (int ni = 0; ni < 2; ni++) {
    int f0 = bn * 64 + wn * 32 + ni * 16 + quad * 4;
    float4 b4 = *(const float4*)(bias + f0);
#pragma unroll
    for (int mi = 0; mi < 2; mi++) {
      int tok = bm * 64 + wm * 32 + mi * 16 + col;
      float4 ov;
      ov.x = acc[mi][ni][0] + b4.x;
      ov.y = acc[mi][ni][1] + b4.y;
      ov.z = acc[mi][ni][2] + b4.z;
      ov.w = acc[mi][ni][3] + b4.w;
      *(float4*)(outp + (size_t)tok * 1024 + f0) = ov;
    }
  }
}

// ---------------------------------------------------------------------------
// Flash attention (causal), transposed-S form:
//  * qt permutation: each CU's 4 resident blocks sum to exactly 66 tiles.
//  * two K/V tiles staged per barrier pair (double LDS buffers).
//  * P strip now XOR-SWIZZLED unpadded Pl[4][16*64] (8 KB): ONE lgkm drain
//    per tile (round 8 had two). LDS 40 KB -> still 4 blocks/CU.
// No running max (|s| <= ~4 after 1/32 prescale -> exp safe in f32).
// ---------------------------------------------------------------------------
__global__ __launch_bounds__(256, 4) void attn_kernel(
    const bf16* __restrict__ qb, const bf16* __restrict__ kb,
    const bf16* __restrict__ vtb, bf16* __restrict__ y) {
  __shared__ bf16 Ks[2][64 * 64];  // swizzled K tiles  [t][d]
  __shared__ bf16 Vs[2][64 * 64];  // swizzled V^T tiles [d][t]
  __shared__ bf16 Pl[4][16 * 64];  // per-wave swizzled P strip [q][t]

  int idx = blockIdx.x;
  int qp = idx >> 5;
  int qt = (qp < 8) ? 31 - qp
           : (qp < 16) ? qp - 8
           : (qp < 24) ? 39 - qp
                       : qp - 16;
  int bh = idx & 31;
  int b = bh >> 4, h = bh & 15;
  int tid = threadIdx.x, w = tid >> 6, lane = tid & 63;
  int col = lane & 15, quad = lane >> 4;

  const bf16* Qh = qb + (size_t)bh * (2048 * 64);
  const bf16* Kh = kb + (size_t)bh * (2048 * 64);
  const bf16* Vth = vtb + (size_t)bh * (64 * 2048);

  // Q frags (B-operand of S^T = K*Q^T), pre-scaled by 1/32 (exact)
  int qrow = qt * 64 + w * 16 + col;
  bf16x8 aq[2];
#pragma unroll
  for (int ks = 0; ks < 2; ks++) {
    aq[ks] = *(const bf16x8*)(Qh + (size_t)qrow * 64 + ks * 32 + quad * 8);
#pragma unroll
    for (int e = 0; e < 8; e++)
      aq[ks][e] = (bf16)((float)aq[ks][e] * 0.03125f);
  }

  int r0 = w * 16 + (lane >> 3);
  int r1 = r0 + 8;
  int ch0 = (lane & 7) ^ (r0 & 7);
  int ch1 = (lane & 7) ^ (r1 & 7);
  size_t koff0 = (size_t)r0 * 64 + ch0 * 8;
  size_t koff1 = (size_t)r1 * 64 + ch1 * 8;
  size_t voff0 = (size_t)r0 * 2048 + ch0 * 8;
  size_t voff1 = (size_t)r1 * 2048 + ch1 * 8;
  int lw0 = (w * 16) * 64;
  int lw1 = (w * 16 + 8) * 64;

  float l_part = 0.f;
  f32x4 ot[4] = {};
  int qglob = qt * 64 + w * 16 + col;

  // P strip addresses (swizzled in 16B chunks: chunk ^= (q&7))
  bf16* PlW = Pl[w];
  int pq = col & 7;  // q-row swizzle key

  auto stage = [&](int j, int buf) {
    const bf16* Kt = Kh + (size_t)j * 64 * 64;
    const bf16* Vt_ = Vth + (size_t)j * 64;
    async_copy16(Kt + koff0, Ks[buf] + lw0);
    async_copy16(Kt + koff1, Ks[buf] + lw1);
    async_copy16(Vt_ + voff0, Vs[buf] + lw0);
    async_copy16(Vt_ + voff1, Vs[buf] + lw1);
  };

  auto tile_compute = [&](int j, int buf, bool diag) {
    const bf16* Ksb = Ks[buf];
    const bf16* Vsb = Vs[buf];
    f32x4 st[4] = {};
#pragma unroll
    for (int ks = 0; ks < 2; ks++)
#pragma unroll
      for (int c = 0; c < 4; c++) {
        int t = c * 16 + col;
        int slot = t * 8 + (((ks << 2) + quad) ^ (t & 7));
        bf16x8 ak = *(const bf16x8*)(Ksb + slot * 8);
        st[c] = __builtin_amdgcn_mfma_f32_16x16x32_bf16(ak, aq[ks], st[c],
                                                        0, 0, 0);
      }
    // exp + causal mask + spill whole 64-t strip (4x b64, swizzled chunks)
#pragma unroll
    for (int c = 0; c < 4; c++) {
      bf16x4 pk;
#pragma unroll
      for (int r = 0; r < 4; r++) {
        int tglob = j * 64 + c * 16 + quad * 4 + r;
        float pv = (diag && tglob > qglob) ? 0.f : __expf(st[c][r]);
        l_part += pv;
        pk[r] = (bf16)pv;
      }
      int chunk = ((c << 1) + (quad >> 1)) ^ pq;
      *(bf16x4*)(PlW + col * 64 + chunk * 8 + (quad & 1) * 4) = pk;
    }

    __builtin_amdgcn_sched_barrier(0);
    __builtin_amdgcn_s_waitcnt(0xc07f);  // lgkmcnt(0): strip visible
    __builtin_amdgcn_sched_barrier(0);

#pragma unroll
    for (int half = 0; half < 2; half++) {
      int pchunk = ((half << 2) + quad) ^ pq;
      bf16x8 ap = *(const bf16x8*)(PlW + col * 64 + pchunk * 8);
#pragma unroll
      for (int c = 0; c < 4; c++) {
        int d = c * 16 + col;
        int slot = d * 8 + (((half << 2) + quad) ^ (d & 7));
        bf16x8 av = *(const bf16x8*)(Vsb + slot * 8);
        ot[c] = __builtin_amdgcn_mfma_f32_16x16x32_bf16(av, ap, ot[c],
                                                        0, 0, 0);
      }
    }
  };

  int j = 0;
  for (; j < qt; j += 2) {
    __syncthreads();
    stage(j, 0);
    stage(j + 1, 1);
    __syncthreads();
    tile_compute(j, 0, false);
    tile_compute(j + 1, 1, j + 1 == qt);
  }
  if (j == qt) {
    __syncthreads();
    stage(j, 0);
    __syncthreads();
    tile_compute(j, 0, true);
  }

  float sum = l_part;
  sum += __shfl_xor(sum, 16, 64);
  sum += __shfl_xor(sum, 32, 64);
  float inv = 1.f / sum;
  int tq = qt * 64 + w * 16 + col;
  bf16* yrow = y + ((size_t)(b * 2048 + tq)) * 1024 + h * 64;
#pragma unroll
  for (int c = 0; c < 4; c++) {
    bf16x4 pk;
#pragma unroll
    for (int r = 0; r < 4; r++) pk[r] = (bf16)(ot[c][r] * inv);
    *(bf16x4*)(yrow + c * 16 + quad * 4) = pk;
  }
}

// ---------------------------------------------------------------------------
extern "C" void kernel_launch(void* const* d_in, const int* in_sizes, int n_in,
                              void* d_out, int out_size, void* d_ws,
                              size_t ws_size, hipStream_t stream) {
  const float* x = (const float*)d_in[0];      // [2,2048,1024] f32
  const float* w_qkv = (const float*)d_in[1];  // [1024,3072] f32
  const float* b_qkv = (const float*)d_in[2];  // [3072] f32
  const float* w_o = (const float*)d_in[3];    // [1024,1024] f32
  const float* b_o = (const float*)d_in[4];    // [1024] f32
  float* out = (float*)d_out;                  // [2,2048,1024] f32

  char* p = (char*)d_ws;
  bf16* xb    = (bf16*)p; p += (size_t)4096 * 1024 * 2;
  bf16* wqkvT = (bf16*)p; p += (size_t)3072 * 1024 * 2;
  bf16* woT   = (bf16*)p; p += (size_t)1024 * 1024 * 2;
  bf16* qb    = (bf16*)p; p += (size_t)2 * 16 * 2048 * 64 * 2;
  bf16* kb    = (bf16*)p; p += (size_t)2 * 16 * 2048 * 64 * 2;
  bf16* vtb   = (bf16*)p; p += (size_t)2 * 16 * 64 * 2048 * 2;
  bf16* yb    = (bf16*)p; p += (size_t)4096 * 1024 * 2;

  prep_kernel<<<8192, 256, 0, stream>>>(x, xb, w_qkv, wqkvT, w_o, woT);
  gemm_qkv_kernel<<<dim3(64, 24), 256, 0, stream>>>(
      xb, wqkvT, b_qkv, qb, kb, vtb);
  attn_kernel<<<1024, 256, 0, stream>>>(qb, kb, vtb, yb);
  gemm_out_kernel<<<dim3(64, 16), 256, 0, stream>>>(yb, woT, b_o, out);
}